// Round 8
// baseline (185.411 us; speedup 1.0000x reference)
//
#include <hip/hip_runtime.h>

// ---------------------------------------------------------------------------
// AttentionOT  (Nq=64, M=16, B=8, K=256, C=512)
//   Front (error-critical, feeds exp(20*sim)): bf16x3 split MFMA (Markidis),
//     operands PRE-SPLIT by a memory-bound prep pass.
//   Back half: plain bf16 MFMA, weights precast.
//   Sinkhorn: launch_bounds(256,2), permlane16/32 butterflies, early exit.
//   qkv GEMM (r10-11, verified): 64x128 tiles, gll_lds width-16 dbuf,
//     issue-early/drain-late 2-phase, 768 blocks = 3/CU.
//   Back GEMMs (r12, verified −6.4us): same schedule, 512 blocks = 2/CU.
//   Round 13: sim64 ported to the same gll_lds dbuf schedule. Its fused
//     rownorm moved to the qkv epilogue: each q/k block shfl-reduces its
//     row ssq partials and atomicAdds into rs[] (zeroed by prep's last
//     block); sim64 applies 1/sqrt(rs) in the epilogue. One barrier/step
//     instead of two, zero staging VALU in sim64.
//   6 dispatches: prep -> qkv -> sim -> sinkhorn -> T@V -> proj.
// ---------------------------------------------------------------------------

typedef short   short8  __attribute__((ext_vector_type(8)));
typedef float   floatx4 __attribute__((ext_vector_type(4)));
typedef unsigned int uint2e __attribute__((ext_vector_type(2)));

static __device__ __forceinline__ float fastrcp(float x) {
    return __builtin_amdgcn_rcpf(x);
}
static __device__ __forceinline__ unsigned short f2bf(float f) {
    union { float f; unsigned u; } c; c.f = f;
    unsigned r = c.u + 0x7FFF + ((c.u >> 16) & 1);   // RNE
    return (unsigned short)(r >> 16);
}
static __device__ __forceinline__ float bf2f(unsigned short h) {
    union { unsigned u; float f; } c; c.u = (unsigned)h << 16;
    return c.f;
}

// HBM -> LDS direct DMA, 16B per lane. LDS dest is wave-uniform base;
// HW writes lane i at base + i*16 (m03/m97/m104).
static __device__ __forceinline__ void gll16(const unsigned short* g, short* l) {
    __builtin_amdgcn_global_load_lds(
        (const __attribute__((address_space(1))) void*)g,
        (__attribute__((address_space(3))) void*)l, 16, 0, 0);
}

// Cross-lane butterfly adds via gfx950 permlane16/32_swap.
#if __has_builtin(__builtin_amdgcn_permlane16_swap)
static __device__ __forceinline__ float xadd16(float s) {
    uint2e r = __builtin_amdgcn_permlane16_swap(
        __float_as_uint(s), __float_as_uint(s), false, false);
    return __uint_as_float(r.x) + __uint_as_float(r.y);
}
#else
static __device__ __forceinline__ float xadd16(float s) {
    return s + __shfl_xor(s, 16, 64);
}
#endif
#if __has_builtin(__builtin_amdgcn_permlane32_swap)
static __device__ __forceinline__ float xadd32(float s) {
    uint2e r = __builtin_amdgcn_permlane32_swap(
        __float_as_uint(s), __float_as_uint(s), false, false);
    return __uint_as_float(r.x) + __uint_as_float(r.y);
}
#else
static __device__ __forceinline__ float xadd32(float s) {
    return s + __shfl_xor(s, 32, 64);
}
#endif

#define RRI(x, C) __builtin_amdgcn_update_dpp(0, (x), (C), 0xf, 0xf, true)
#define RRF(x, C) __int_as_float(RRI(__float_as_int(x), (C)))
#define GATH16(d, s) do { d[0] = (s);                                        \
    d[1]  = RRF((s), 0x121); d[2]  = RRF((s), 0x122);                        \
    d[3]  = RRF((s), 0x123); d[4]  = RRF((s), 0x124);                        \
    d[5]  = RRF((s), 0x125); d[6]  = RRF((s), 0x126);                        \
    d[7]  = RRF((s), 0x127); d[8]  = RRF((s), 0x128);                        \
    d[9]  = RRF((s), 0x129); d[10] = RRF((s), 0x12a);                        \
    d[11] = RRF((s), 0x12b); d[12] = RRF((s), 0x12c);                        \
    d[13] = RRF((s), 0x12d); d[14] = RRF((s), 0x12e);                        \
    d[15] = RRF((s), 0x12f); } while (0)

// ---------------------------------------------------------------------------
// prep: fp32 -> bf16 split (xq,xk,Wq,Wk) / cast (xv,Wv,Wp).  Last block
// also zeroes the rs[] norm accumulator (10240 floats) — ordered before
// qkv by the kernel boundary.
// ---------------------------------------------------------------------------
__global__ __launch_bounds__(256) void prep(
    const float* __restrict__ xq, const float* __restrict__ xk,
    const float* __restrict__ xv, const float* __restrict__ Wq,
    const float* __restrict__ Wk, const float* __restrict__ Wv,
    const float* __restrict__ Wp,
    unsigned short* __restrict__ xqh, unsigned short* __restrict__ xql,
    unsigned short* __restrict__ xkh, unsigned short* __restrict__ xkl,
    unsigned short* __restrict__ xvb,
    unsigned short* __restrict__ wqh, unsigned short* __restrict__ wql,
    unsigned short* __restrict__ wkh, unsigned short* __restrict__ wkl,
    unsigned short* __restrict__ wvb, unsigned short* __restrict__ wpb,
    float* __restrict__ rs)
{
    const int b = blockIdx.x;
    const float* src; unsigned short *dh, *dl; long base;
    if (b < 4096)      { src = xq; dh = xqh; dl = xql;     base = (long)b * 256; }
    else if (b < 5120) { src = xk; dh = xkh; dl = xkl;     base = (long)(b - 4096) * 256; }
    else if (b < 6144) { src = xv; dh = xvb; dl = nullptr; base = (long)(b - 5120) * 256; }
    else if (b < 6400) { src = Wq; dh = wqh; dl = wql;     base = (long)(b - 6144) * 256; }
    else if (b < 6656) { src = Wk; dh = wkh; dl = wkl;     base = (long)(b - 6400) * 256; }
    else if (b < 6912) { src = Wv; dh = wvb; dl = nullptr; base = (long)(b - 6656) * 256; }
    else               { src = Wp; dh = wpb; dl = nullptr; base = (long)(b - 6912) * 256; }
    const long i = base + threadIdx.x;
    float4 v = ((const float4*)src)[i];
    ushort4 h;
    h.x = f2bf(v.x); h.y = f2bf(v.y); h.z = f2bf(v.z); h.w = f2bf(v.w);
    ((ushort4*)dh)[i] = h;
    if (dl) {
        ushort4 l;
        l.x = f2bf(v.x - bf2f(h.x)); l.y = f2bf(v.y - bf2f(h.y));
        l.z = f2bf(v.z - bf2f(h.z)); l.w = f2bf(v.w - bf2f(h.w));
        ((ushort4*)dl)[i] = l;
    }
    if (b == 7167) {
#pragma unroll
        for (int ii = 0; ii < 40; ii++) rs[threadIdx.x + ii * 256] = 0.0f;
    }
}

// ---------------------------------------------------------------------------
// Fused q/k/v projection.  64x128 tiles, BK=32, 768 blocks (3/CU).
// gll_lds dbuf 2-phase (verified r10-11).  Round 13: q/k epilogue also
// accumulates row sum-of-squares (of the h+lo reconstruction, identical to
// the old rownorm) via 16-lane shfl reduce + one atomicAdd per row.
// ---------------------------------------------------------------------------
__global__ __launch_bounds__(256, 3) void gemm_qkv2(
    const unsigned short* __restrict__ xqh, const unsigned short* __restrict__ xql,
    const unsigned short* __restrict__ xkh, const unsigned short* __restrict__ xkl,
    const unsigned short* __restrict__ xvb,
    const unsigned short* __restrict__ wqh, const unsigned short* __restrict__ wql,
    const unsigned short* __restrict__ wkh, const unsigned short* __restrict__ wkl,
    const unsigned short* __restrict__ wvb,
    unsigned short* __restrict__ qh, unsigned short* __restrict__ ql,
    unsigned short* __restrict__ kh, unsigned short* __restrict__ kl,
    unsigned short* __restrict__ vt, float* __restrict__ rs)
{
    __shared__ __align__(16) short LB[24576];          // 48 KB (2 x 24KB)

    const int bt = blockIdx.x;
    const unsigned short *Ah, *Al, *Bh, *Bl;
    int seg, arow0;
    if (bt < 128)      { Ah = xqh; Al = xql; Bh = wqh; Bl = wql; arow0 = bt * 64;         seg = 0; }
    else if (bt < 160) { Ah = xkh; Al = xkl; Bh = wkh; Bl = wkl; arow0 = (bt - 128) * 64; seg = 1; }
    else               { Ah = xvb; Al = xvb; Bh = wvb; Bl = wvb; arow0 = (bt - 160) * 64; seg = 2; }
    const bool split = (seg != 2);

    const int tid  = threadIdx.x;
    const int lane = tid & 63, wv = tid >> 6;
    const int wc = wv * 32;                            // wave col slice
    const int j0 = blockIdx.y * 128;

    floatx4 acc[4][2];
#pragma unroll
    for (int i = 0; i < 4; i++)
#pragma unroll
        for (int j = 0; j < 2; j++) acc[i][j] = {0.f, 0.f, 0.f, 0.f};

    const int lrow = lane >> 2;
    const int lch  = (lane & 3) * 8;
    const int gra  = 16 * wv;                          // A wave row base
    const int grb  = 32 * wv;                          // B wave row base
    const long gA0 = (long)(arow0 + gra + lrow) * 512 + lch;
    const long gB0 = (long)(j0    + grb + lrow) * 512 + lch;

    const int fr = lane & 15, fq = (lane >> 4) * 8;

#define QKV_STAGE(d, k0) do {                                                 \
        short* bb = LB + (d) * 12288;                                         \
        gll16(Ah + gA0 + (k0),            bb + gra * 32);                     \
        gll16(Bh + gB0 + (k0),            bb + 4096 + grb * 32);              \
        gll16(Bh + gB0 + (k0) + 16 * 512, bb + 4096 + (grb + 16) * 32);       \
        if (split) {                                                          \
            gll16(Al + gA0 + (k0),            bb + 2048 + gra * 32);          \
            gll16(Bl + gB0 + (k0),            bb + 8192 + grb * 32);          \
            gll16(Bl + gB0 + (k0) + 16 * 512, bb + 8192 + (grb + 16) * 32);   \
        }                                                                     \
    } while (0)

    QKV_STAGE(0, 0);
    __syncthreads();                        // tile 0 ready

#pragma unroll 2
    for (int t = 0; t < 16; t++) {
        const int cur = t & 1;
        if (t < 15) QKV_STAGE(cur ^ 1, (t + 1) * 32);   // issue-early
        const short* base = LB + cur * 12288;
        short8 ah[4], bh[2];
#pragma unroll
        for (int i = 0; i < 4; i++)
            ah[i] = *(const short8*)&base[(i * 16 + fr) * 32 + fq];
#pragma unroll
        for (int j = 0; j < 2; j++)
            bh[j] = *(const short8*)&base[4096 + (wc + j * 16 + fr) * 32 + fq];
        if (split) {
            short8 al[4], bl[2];
#pragma unroll
            for (int i = 0; i < 4; i++)
                al[i] = *(const short8*)&base[2048 + (i * 16 + fr) * 32 + fq];
#pragma unroll
            for (int j = 0; j < 2; j++)
                bl[j] = *(const short8*)&base[8192 + (wc + j * 16 + fr) * 32 + fq];
#pragma unroll
            for (int i = 0; i < 4; i++)
#pragma unroll
                for (int j = 0; j < 2; j++) {
                    acc[i][j] = __builtin_amdgcn_mfma_f32_16x16x32_bf16(ah[i], bh[j], acc[i][j], 0, 0, 0);
                    acc[i][j] = __builtin_amdgcn_mfma_f32_16x16x32_bf16(ah[i], bl[j], acc[i][j], 0, 0, 0);
                    acc[i][j] = __builtin_amdgcn_mfma_f32_16x16x32_bf16(al[i], bh[j], acc[i][j], 0, 0, 0);
                }
        } else {
#pragma unroll
            for (int i = 0; i < 4; i++)
#pragma unroll
                for (int j = 0; j < 2; j++)
                    acc[i][j] = __builtin_amdgcn_mfma_f32_16x16x32_bf16(ah[i], bh[j], acc[i][j], 0, 0, 0);
        }
        __syncthreads();                    // drain-late: vmcnt after compute
    }
#undef QKV_STAGE

    const int cr = (lane >> 4) * 4, cc = lane & 15;
    if (seg == 2) {
        // LDS transpose: S2[c_local][k'_local], rows padded to 72 shorts
        short (*S2)[72] = (short(*)[72])LB;            // 128 x 72 = 18 KB
#pragma unroll
        for (int i = 0; i < 4; i++)
#pragma unroll
            for (int j = 0; j < 2; j++)
#pragma unroll
                for (int r = 0; r < 4; r++)
                    S2[wc + j * 16 + cc][i * 16 + cr + r] =
                        (short)f2bf(acc[i][j][r]);
        __syncthreads();
        const int orow = tid >> 1;            // c_local 0..127
        const int os   = (tid & 1) * 32;      // k'_local chunk
        unsigned short* dst = vt + (long)(arow0 >> 8) * 131072
                            + (long)(j0 + orow) * 256 + (arow0 & 255) + os;
#pragma unroll
        for (int c8 = 0; c8 < 4; c8++)
            *(short8*)(dst + c8 * 8) = *(const short8*)&S2[orow][os + c8 * 8];
    } else {
        float prow[16];
#pragma unroll
        for (int ii = 0; ii < 16; ii++) prow[ii] = 0.0f;
#pragma unroll
        for (int i = 0; i < 4; i++)
#pragma unroll
            for (int j = 0; j < 2; j++) {
                const int gj = j0 + wc + j * 16 + cc;
#pragma unroll
                for (int r = 0; r < 4; r++) {
                    const int gi = arow0 + i * 16 + cr + r;
                    const float v = acc[i][j][r];
                    const unsigned short h = f2bf(v);
                    const unsigned short lo = f2bf(v - bf2f(h));
                    const float vv = bf2f(h) + bf2f(lo);
                    prow[i * 4 + r] = fmaf(vv, vv, prow[i * 4 + r]);
                    if (seg == 0) {
                        const long orow = (long)((gi & 7) * 1024 + ((gi >> 3) & 15) * 64 + (gi >> 7));
                        qh[orow * 512 + gj] = h;
                        ql[orow * 512 + gj] = lo;
                    } else {
                        kh[(long)gi * 512 + gj] = h;
                        kl[(long)gi * 512 + gj] = lo;
                    }
                }
            }
        // row-norm partials (this block's 128 cols) -> rs accumulator
#pragma unroll
        for (int i = 0; i < 4; i++)
#pragma unroll
            for (int r = 0; r < 4; r++) {
                float p = prow[i * 4 + r];
                p += __shfl_xor(p, 1, 64);
                p += __shfl_xor(p, 2, 64);
                p += __shfl_xor(p, 4, 64);
                p += __shfl_xor(p, 8, 64);
                if (cc == 0) {
                    const int gi = arow0 + i * 16 + cr + r;
                    long ri;
                    if (seg == 0)
                        ri = (long)((gi & 7) * 1024 + ((gi >> 3) & 15) * 64 + (gi >> 7));
                    else
                        ri = 8192 + (long)gi;
                    atomicAdd(rs + ri, p);
                }
            }
    }
}

// ---------------------------------------------------------------------------
// sim GEMM, 64x64 tiles (512 blocks), bf16x3.  Round 13: gll_lds width-16
// dbuf issue-early/drain-late 2-phase (proven schedule), one barrier/step.
// Norms arrive precomputed in rs[] (ssq sums); epilogue applies
// 1/sqrt.  Per buffer (shorts): Ash[64][32]@0, Asl@2048, Bsh@4096, Bsl@6144.
// ---------------------------------------------------------------------------
__global__ __launch_bounds__(256, 2) void gemm_sim64(
    const unsigned short* __restrict__ Ah, const unsigned short* __restrict__ Al,
    const unsigned short* __restrict__ Bh, const unsigned short* __restrict__ Bl,
    float* __restrict__ Out, const float* __restrict__ rs)
{
    const int z = blockIdx.z;
    Ah += (long)z * 131072;  Al += (long)z * 131072;
    Bh += (long)z * 524288;  Bl += (long)z * 524288;
    Out += (long)z * 262144;
    const float* rsq = rs + (long)z * 1024;
    const float* rsk = rs + 8192 + (long)z * 256;

    __shared__ __align__(16) short LB[16384];          // 32 KB (2 x 16KB)

    const int tid  = threadIdx.x;
    const int lane = tid & 63, wv = tid >> 6;
    const int wr = (wv >> 1) * 32, wc = (wv & 1) * 32;
    const int i0 = blockIdx.x * 64, j0 = blockIdx.y * 64;

    floatx4 acc[2][2];
#pragma unroll
    for (int i = 0; i < 2; i++)
#pragma unroll
        for (int j = 0; j < 2; j++) acc[i][j] = {0.f, 0.f, 0.f, 0.f};

    const int lrow = lane >> 2;
    const int lch  = (lane & 3) * 8;
    const int gr   = 16 * wv;                          // wave row base
    const long gA0 = (long)(i0 + gr + lrow) * 512 + lch;
    const long gB0 = (long)(j0 + gr + lrow) * 512 + lch;

    const int fr = lane & 15, fq = (lane >> 4) * 8;

#define SIM_STAGE(d, k0) do {                                                 \
        short* bb = LB + (d) * 8192;                                          \
        gll16(Ah + gA0 + (k0), bb + gr * 32);                                 \
        gll16(Al + gA0 + (k0), bb + 2048 + gr * 32);                          \
        gll16(Bh + gB0 + (k0), bb + 4096 + gr * 32);                          \
        gll16(Bl + gB0 + (k0), bb + 6144 + gr * 32);                          \
    } while (0)

    SIM_STAGE(0, 0);
    __syncthreads();

#pragma unroll 2
    for (int t = 0; t < 16; t++) {
        const int cur = t & 1;
        if (t < 15) SIM_STAGE(cur ^ 1, (t + 1) * 32);   // issue-early
        const short* base = LB + cur * 8192;
        short8 ah[2], al[2], bh[2], bl[2];
#pragma unroll
        for (int i = 0; i < 2; i++) {
            ah[i] = *(const short8*)&base[(wr + i * 16 + fr) * 32 + fq];
            al[i] = *(const short8*)&base[2048 + (wr + i * 16 + fr) * 32 + fq];
        }
#pragma unroll
        for (int j = 0; j < 2; j++) {
            bh[j] = *(const short8*)&base[4096 + (wc + j * 16 + fr) * 32 + fq];
            bl[j] = *(const short8*)&base[6144 + (wc + j * 16 + fr) * 32 + fq];
        }
#pragma unroll
        for (int i = 0; i < 2; i++)
#pragma unroll
            for (int j = 0; j < 2; j++) {
                acc[i][j] = __builtin_amdgcn_mfma_f32_16x16x32_bf16(ah[i], bh[j], acc[i][j], 0, 0, 0);
                acc[i][j] = __builtin_amdgcn_mfma_f32_16x16x32_bf16(ah[i], bl[j], acc[i][j], 0, 0, 0);
                acc[i][j] = __builtin_amdgcn_mfma_f32_16x16x32_bf16(al[i], bh[j], acc[i][j], 0, 0, 0);
            }
        __syncthreads();                    // drain-late
    }
#undef SIM_STAGE

    const int cr = (lane >> 4) * 4, cc = lane & 15;
#pragma unroll
    for (int i = 0; i < 2; i++)
#pragma unroll
        for (int j = 0; j < 2; j++) {
            const int lc = wc + j * 16 + cc;
            const float sq = 1.0f / fmaxf(sqrtf(rsq[j0 + lc]), 1e-12f);
            const int gj = j0 + lc;
#pragma unroll
            for (int r = 0; r < 4; r++) {
                const int lr = wr + i * 16 + cr + r;
                const float sa = 1.0f / fmaxf(sqrtf(rsk[i0 + lr]), 1e-12f);
                Out[(long)(i0 + lr) * 1024 + gj] = acc[i][j][r] * sa * sq;
            }
        }
}

// ---------------------------------------------------------------------------
// Plain bf16 MFMA GEMM v2 (T@V and final proj): 64x128 tiles, BK=32,
// gll_lds width-16 dbuf, issue-early/drain-late 2-phase (verified r12).
// ---------------------------------------------------------------------------
template <bool BIAS, bool OPERM, bool OUT_BF16>
__global__ __launch_bounds__(256, 2) void gemm_bf16_v2(
    const unsigned short* __restrict__ A, const unsigned short* __restrict__ B,
    const float* __restrict__ bias, void* __restrict__ OutV,
    int Kdim, int lda, int ldb, int ldo, long sA, long sB, long sO)
{
    __shared__ __align__(16) short LB[12288];          // 24 KB (2 x 12KB)

    const int tid  = threadIdx.x;
    const int lane = tid & 63, wv = tid >> 6;
    const int wc = wv * 32;
    const int i0 = blockIdx.x * 64, j0 = blockIdx.y * 128;

    floatx4 acc[4][2];
#pragma unroll
    for (int i = 0; i < 4; i++)
#pragma unroll
        for (int j = 0; j < 2; j++) acc[i][j] = {0.f, 0.f, 0.f, 0.f};

    const unsigned short* pa = A + (long)blockIdx.z * sA;
    const unsigned short* pb = B + (long)blockIdx.z * sB;

    const int lrow = lane >> 2;
    const int lch  = (lane & 3) * 8;
    const int gra  = 16 * wv;                          // A wave row base
    const int grb  = 32 * wv;                          // B wave row base
    const long gA0 = (long)(i0 + gra + lrow) * lda + lch;
    const long gB0 = (long)(j0 + grb + lrow) * ldb + lch;

    const int fr = lane & 15, fq = (lane >> 4) * 8;

#define BF2_STAGE(d, k0) do {                                                 \
        short* bb = LB + (d) * 6144;                                          \
        gll16(pa + gA0 + (k0),             bb + gra * 32);                    \
        gll16(pb + gB0 + (k0),             bb + 2048 + grb * 32);             \
        gll16(pb + gB0 + (k0) + 16 * ldb,  bb + 2048 + (grb + 16) * 32);      \
    } while (0)

    const int nt = Kdim >> 5;
    BF2_STAGE(0, 0);
    __syncthreads();

#pragma unroll 2
    for (int t = 0; t < nt; t++) {
        const int cur = t & 1;
        if (t < nt - 1) BF2_STAGE(cur ^ 1, (t + 1) * 32);   // issue-early
        const short* base = LB + cur * 6144;
        short8 af[4], bf[2];
#pragma unroll
        for (int i = 0; i < 4; i++)
            af[i] = *(const short8*)&base[(i * 16 + fr) * 32 + fq];
#pragma unroll
        for (int j = 0; j < 2; j++)
            bf[j] = *(const short8*)&base[2048 + (wc + j * 16 + fr) * 32 + fq];
#pragma unroll
        for (int i = 0; i < 4; i++)
#pragma unroll
            for (int j = 0; j < 2; j++)
                acc[i][j] = __builtin_amdgcn_mfma_f32_16x16x32_bf16(af[i], bf[j], acc[i][j], 0, 0, 0);
        __syncthreads();                    // drain-late
    }
#undef BF2_STAGE

    float* Of = nullptr; unsigned short* Ob = nullptr;
    if constexpr (OUT_BF16) Ob = (unsigned short*)OutV + (long)blockIdx.z * sO;
    else                    Of = (float*)OutV + (long)blockIdx.z * sO;
    const int cr = (lane >> 4) * 4, cc = lane & 15;
#pragma unroll
    for (int i = 0; i < 4; i++) {
#pragma unroll
        for (int j = 0; j < 2; j++) {
            const int gj = j0 + wc + j * 16 + cc;
            float bb = 0.0f;
            if constexpr (BIAS) bb = bias[gj];
#pragma unroll
            for (int r = 0; r < 4; r++) {
                const int gi = i0 + i * 16 + cr + r;
                float v = acc[i][j][r] + bb;
                long idx;
                if constexpr (OPERM)
                    idx = (long)((gi & 63) * 128 + ((gi >> 6) & 15) * 8 + (gi >> 10)) * ldo + gj;
                else
                    idx = (long)gi * ldo + gj;
                if constexpr (OUT_BF16) Ob[idx] = f2bf(v);
                else                    Of[idx] = v;
            }
        }
    }
}

// ---------------------------------------------------------------------------
// Sinkhorn, rotated dual layouts + DPP + permlane butterflies + early exit.
// ---------------------------------------------------------------------------
__global__ __launch_bounds__(256, 2) void sinkhorn5(
    const float* __restrict__ sim, float* __restrict__ score,
    unsigned short* __restrict__ Tt)
{
    const int lane = threadIdx.x & 63;
    const int bk   = blockIdx.x * 4 + (threadIdx.x >> 6);
    const float* S = sim + (long)bk * 1024;
    const int m = lane & 15, g = lane >> 4;

    int idx[16];
    idx[0] = m;
    idx[1]  = RRI(m, 0x121); idx[2]  = RRI(m, 0x122); idx[3]  = RRI(m, 0x123);
    idx[4]  = RRI(m, 0x124); idx[5]  = RRI(m, 0x125); idx[6]  = RRI(m, 0x126);
    idx[7]  = RRI(m, 0x127); idx[8]  = RRI(m, 0x128); idx[9]  = RRI(m, 0x129);
    idx[10] = RRI(m, 0x12a); idx[11] = RRI(m, 0x12b); idx[12] = RRI(m, 0x12c);
    idx[13] = RRI(m, 0x12d); idx[14] = RRI(m, 0x12e); idx[15] = RRI(m, 0x12f);

    float K1[16], K2R[16], sv[16];
#pragma unroll
    for (int j = 0; j < 16; j++) {
        K1[j] = __expf((S[m * 64 + g * 16 + idx[j]] - 1.0f) * 20.0f);
        const float s_ = S[idx[j] * 64 + lane];
        sv[j]  = s_;
        K2R[j] = __expf((s_ - 1.0f) * 20.0f);
    }

    const float muP = 0.0625f + 1e-8f;
    const float nuP = 0.015625f + 1e-8f;
    float b = 1.0f;
    float aB[16], bB[16];
#pragma unroll
    for (int j = 0; j < 16; j++) bB[j] = 1.0f;

#pragma unroll 1
    for (int it = 0; it < 100; it++) {
        float s0 = 0, s1 = 0, s2 = 0, s3 = 0;
#pragma unroll
        for (int j = 0; j < 4; j++) {
            s0 = fmaf(K1[j],      bB[j],      s0);
            s1 = fmaf(K1[4 + j],  bB[4 + j],  s1);
            s2 = fmaf(K1[8 + j],  bB[8 + j],  s2);
            s3 = fmaf(K1[12 + j], bB[12 + j], s3);
        }
        float s = (s0 + s1) + (s2 + s3);
        s = xadd16(s);
        s = xadd32(s);
        const float a = muP * fastrcp(s);
        GATH16(aB, a);
        float t0 = 0, t1 = 0, t2 = 0, t3 = 0;
#pragma unroll
        for (int j = 0; j < 4; j++) {
            t0 = fmaf(K2R[j],      aB[j],      t0);
            t1 = fmaf(K2R[4 + j],  aB[4 + j],  t1);
            t2 = fmaf(K2R[8 + j],  aB[8 + j],  t2);
            t3 = fmaf(K2R[12 + j], aB[12 + j], t3);
        }
        const float bp_ = b;
        b = nuP * fastrcp((t0 + t1) + (t2 + t3));
        GATH16(bB, b);
        const int conv = __builtin_fabsf(b - bp_) <= 1e-5f * __builtin_fabsf(b);
        if (__all(conv)) break;
    }

    float* Sc = score + (long)bk * 1024;
    unsigned short* Tp = Tt + (long)(bk >> 8) * 262144 + (bk & 255);
#pragma unroll
    for (int j = 0; j < 16; j++) {
        const int row = idx[j];
        const float Tv = aB[j] * K2R[j] * b;
        Sc[row * 64 + lane] = 1024.0f * sv[j] * Tv;
        Tp[(long)(row * 64 + lane) * 256] = f2bf(Tv);
    }
}

extern "C" void kernel_launch(void* const* d_in, const int* in_sizes, int n_in,
                              void* d_out, int out_size, void* d_ws, size_t ws_size,
                              hipStream_t stream)
{
    (void)in_sizes; (void)n_in; (void)out_size; (void)ws_size;
    const float* xq = (const float*)d_in[0];
    const float* xk = (const float*)d_in[1];
    const float* xv = (const float*)d_in[2];
    const float* Wq = (const float*)d_in[3];
    const float* Wk = (const float*)d_in[4];
    const float* Wv = (const float*)d_in[5];
    const float* Wp = (const float*)d_in[6];
    const float* bp = (const float*)d_in[7];

    float* out_x     = (float*)d_out;           // (Nq,M,B,C) = 8192 x 512
    float* out_score = out_x + 8192L * 512;     // (B,K,M,Nq) = 2048 x 1024

    // workspace (47 MB of the proven 48 MB); regions reused across phases
    char* W = (char*)d_ws;
    const long MB = 1 << 20;
    unsigned short* qh   = (unsigned short*)(W + 0);        // 8MB [b][mn][c]
    unsigned short* ql   = (unsigned short*)(W + 8 * MB);   // 8MB
    unsigned short* xq_h = (unsigned short*)(W + 16 * MB);  // 8MB, dead after qkv
    float*          simb = (float*)(W + 16 * MB);           // 8MB (reuse)
    unsigned short* xq_l = (unsigned short*)(W + 24 * MB);  // 8MB, dead after qkv
    unsigned short* xpre = (unsigned short*)(W + 24 * MB);  // 8MB (reuse)
    unsigned short* xk_h = (unsigned short*)(W + 32 * MB);  // 2MB, dead after qkv
    unsigned short* xk_l = (unsigned short*)(W + 34 * MB);  // 2MB
    unsigned short* Tt   = (unsigned short*)(W + 32 * MB);  // 4MB (reuse)
    unsigned short* xv_b = (unsigned short*)(W + 36 * MB);  // 2MB
    unsigned short* kh   = (unsigned short*)(W + 38 * MB);  // 2MB [b][k'][c]
    unsigned short* kl   = (unsigned short*)(W + 40 * MB);  // 2MB
    unsigned short* vt   = (unsigned short*)(W + 42 * MB);  // 2MB [b][c][k']
    unsigned short* wqh  = (unsigned short*)(W + 44 * MB);
    unsigned short* wql  = (unsigned short*)(W + 44 * MB + 1 * 524288);
    unsigned short* wkh  = (unsigned short*)(W + 44 * MB + 2 * 524288);
    unsigned short* wkl  = (unsigned short*)(W + 44 * MB + 3 * 524288);
    unsigned short* wvb  = (unsigned short*)(W + 44 * MB + 4 * 524288);
    unsigned short* wpb  = (unsigned short*)(W + 44 * MB + 5 * 524288);
    float*          rs   = (float*)(W + 47 * MB);           // 40KB ssq accum

    const dim3 blk(256);

    // 1: precast/split all fp32 operands + zero rs (memory-bound)
    prep<<<7168, blk, 0, stream>>>(xq, xk, xv, Wq, Wk, Wv, Wp,
                                   xq_h, xq_l, xk_h, xk_l, xv_b,
                                   wqh, wql, wkh, wkl, wvb, wpb, rs);

    // 2: fused q/k/v projections (64x128 tiles, 3/CU, gll_lds dbuf)
    //    + row-ssq accumulation into rs via atomics
    gemm_qkv2<<<dim3(192, 4), blk, 0, stream>>>(
        xq_h, xq_l, xk_h, xk_l, xv_b, wqh, wql, wkh, wkl, wvb,
        qh, ql, kh, kl, vt, rs);

    // 3: sim[b][k'][mn] = (k.q) * rs_k * rs_q  (gll_lds dbuf; norms from rs)
    gemm_sim64<<<dim3(4, 16, 8), blk, 0, stream>>>(
        xq_h ? (const unsigned short*)kh : nullptr, (const unsigned short*)kl,
        (const unsigned short*)qh, (const unsigned short*)ql,
        simb, rs);

    // 4: Sinkhorn -> score (out) + T bf16 [b][mn][k']
    sinkhorn5<<<512, blk, 0, stream>>>(simb, out_score, Tt);

    // 5: xpre[b][mn][c] = sum_k' T[b][mn][k'] * v[b][k'][c]
    gemm_bf16_v2<false, false, true><<<dim3(16, 4, 8), blk, 0, stream>>>(
        Tt, vt, nullptr, xpre,
        256, 256, 256, 512, 262144, 131072, 524288);

    // 6: x = xpre @ Wp^T + bp, rows (b,mn)->(n,m,b), fp32 out
    gemm_bf16_v2<true, true, false><<<dim3(128, 4), blk, 0, stream>>>(
        xpre, wpb, bp, out_x,
        512, 512, 512, 512, 0, 0, 0);
}

// Round 9
// 179.025 us; speedup vs baseline: 1.0357x; 1.0357x over previous
//
#include <hip/hip_runtime.h>

// ---------------------------------------------------------------------------
// AttentionOT  (Nq=64, M=16, B=8, K=256, C=512)
//   Front (error-critical, feeds exp(20*sim)): bf16x3 split MFMA (Markidis),
//     operands PRE-SPLIT by a memory-bound prep pass.
//   Back half: plain bf16 MFMA, weights precast.
//   Sinkhorn: launch_bounds(256,2), permlane16/32 butterflies, early exit.
//   qkv GEMM (r10-11, verified): 64x128 tiles, gll_lds width-16 dbuf,
//     issue-early/drain-late 2-phase, 768 blocks = 3/CU.
//   Back GEMMs (r12, verified): same schedule, 512 blocks = 2/CU.
//   Round 14: r13's bundled change (qkv atomic rownorm + sim64 port)
//     REGRESSED +5us -> full revert to r12 state except sim64, which now
//     gets the gll_lds dbuf schedule with SELF-CONTAINED norms: row ssq
//     accumulated from the MFMA fragments each lane already ds_reads
//     (4 lanes/row cover disjoint 8-elem chunks; xadd16+xadd32 completes
//     the row), wave-uniform predicates avoid double-count. No atomics,
//     no qkv change, numerics identical to the r12 fused rownorm.
//   6 dispatches: prep -> qkv -> sim -> sinkhorn -> T@V -> proj.
// ---------------------------------------------------------------------------

typedef short   short8  __attribute__((ext_vector_type(8)));
typedef float   floatx4 __attribute__((ext_vector_type(4)));
typedef unsigned int uint2e __attribute__((ext_vector_type(2)));

static __device__ __forceinline__ float fastrcp(float x) {
    return __builtin_amdgcn_rcpf(x);
}
static __device__ __forceinline__ unsigned short f2bf(float f) {
    union { float f; unsigned u; } c; c.f = f;
    unsigned r = c.u + 0x7FFF + ((c.u >> 16) & 1);   // RNE
    return (unsigned short)(r >> 16);
}
static __device__ __forceinline__ float bf2f(unsigned short h) {
    union { unsigned u; float f; } c; c.u = (unsigned)h << 16;
    return c.f;
}

// HBM -> LDS direct DMA, 16B per lane. LDS dest is wave-uniform base;
// HW writes lane i at base + i*16 (m03/m97/m104).
static __device__ __forceinline__ void gll16(const unsigned short* g, short* l) {
    __builtin_amdgcn_global_load_lds(
        (const __attribute__((address_space(1))) void*)g,
        (__attribute__((address_space(3))) void*)l, 16, 0, 0);
}

// Cross-lane butterfly adds via gfx950 permlane16/32_swap.
#if __has_builtin(__builtin_amdgcn_permlane16_swap)
static __device__ __forceinline__ float xadd16(float s) {
    uint2e r = __builtin_amdgcn_permlane16_swap(
        __float_as_uint(s), __float_as_uint(s), false, false);
    return __uint_as_float(r.x) + __uint_as_float(r.y);
}
#else
static __device__ __forceinline__ float xadd16(float s) {
    return s + __shfl_xor(s, 16, 64);
}
#endif
#if __has_builtin(__builtin_amdgcn_permlane32_swap)
static __device__ __forceinline__ float xadd32(float s) {
    uint2e r = __builtin_amdgcn_permlane32_swap(
        __float_as_uint(s), __float_as_uint(s), false, false);
    return __uint_as_float(r.x) + __uint_as_float(r.y);
}
#else
static __device__ __forceinline__ float xadd32(float s) {
    return s + __shfl_xor(s, 32, 64);
}
#endif

#define RRI(x, C) __builtin_amdgcn_update_dpp(0, (x), (C), 0xf, 0xf, true)
#define RRF(x, C) __int_as_float(RRI(__float_as_int(x), (C)))
#define GATH16(d, s) do { d[0] = (s);                                        \
    d[1]  = RRF((s), 0x121); d[2]  = RRF((s), 0x122);                        \
    d[3]  = RRF((s), 0x123); d[4]  = RRF((s), 0x124);                        \
    d[5]  = RRF((s), 0x125); d[6]  = RRF((s), 0x126);                        \
    d[7]  = RRF((s), 0x127); d[8]  = RRF((s), 0x128);                        \
    d[9]  = RRF((s), 0x129); d[10] = RRF((s), 0x12a);                        \
    d[11] = RRF((s), 0x12b); d[12] = RRF((s), 0x12c);                        \
    d[13] = RRF((s), 0x12d); d[14] = RRF((s), 0x12e);                        \
    d[15] = RRF((s), 0x12f); } while (0)

// ---------------------------------------------------------------------------
// prep: fp32 -> bf16 split (xq,xk,Wq,Wk) / cast (xv,Wv,Wp).
// ---------------------------------------------------------------------------
__global__ __launch_bounds__(256) void prep(
    const float* __restrict__ xq, const float* __restrict__ xk,
    const float* __restrict__ xv, const float* __restrict__ Wq,
    const float* __restrict__ Wk, const float* __restrict__ Wv,
    const float* __restrict__ Wp,
    unsigned short* __restrict__ xqh, unsigned short* __restrict__ xql,
    unsigned short* __restrict__ xkh, unsigned short* __restrict__ xkl,
    unsigned short* __restrict__ xvb,
    unsigned short* __restrict__ wqh, unsigned short* __restrict__ wql,
    unsigned short* __restrict__ wkh, unsigned short* __restrict__ wkl,
    unsigned short* __restrict__ wvb, unsigned short* __restrict__ wpb)
{
    const int b = blockIdx.x;
    const float* src; unsigned short *dh, *dl; long base;
    if (b < 4096)      { src = xq; dh = xqh; dl = xql;     base = (long)b * 256; }
    else if (b < 5120) { src = xk; dh = xkh; dl = xkl;     base = (long)(b - 4096) * 256; }
    else if (b < 6144) { src = xv; dh = xvb; dl = nullptr; base = (long)(b - 5120) * 256; }
    else if (b < 6400) { src = Wq; dh = wqh; dl = wql;     base = (long)(b - 6144) * 256; }
    else if (b < 6656) { src = Wk; dh = wkh; dl = wkl;     base = (long)(b - 6400) * 256; }
    else if (b < 6912) { src = Wv; dh = wvb; dl = nullptr; base = (long)(b - 6656) * 256; }
    else               { src = Wp; dh = wpb; dl = nullptr; base = (long)(b - 6912) * 256; }
    const long i = base + threadIdx.x;
    float4 v = ((const float4*)src)[i];
    ushort4 h;
    h.x = f2bf(v.x); h.y = f2bf(v.y); h.z = f2bf(v.z); h.w = f2bf(v.w);
    ((ushort4*)dh)[i] = h;
    if (dl) {
        ushort4 l;
        l.x = f2bf(v.x - bf2f(h.x)); l.y = f2bf(v.y - bf2f(h.y));
        l.z = f2bf(v.z - bf2f(h.z)); l.w = f2bf(v.w - bf2f(h.w));
        ((ushort4*)dl)[i] = l;
    }
}

// ---------------------------------------------------------------------------
// Fused q/k/v projection.  64x128 tiles, BK=32, 768 blocks (3/CU).
// gll_lds dbuf 2-phase (verified r10-11).  r7/r12 epilogue (plain stores).
// ---------------------------------------------------------------------------
__global__ __launch_bounds__(256, 3) void gemm_qkv2(
    const unsigned short* __restrict__ xqh, const unsigned short* __restrict__ xql,
    const unsigned short* __restrict__ xkh, const unsigned short* __restrict__ xkl,
    const unsigned short* __restrict__ xvb,
    const unsigned short* __restrict__ wqh, const unsigned short* __restrict__ wql,
    const unsigned short* __restrict__ wkh, const unsigned short* __restrict__ wkl,
    const unsigned short* __restrict__ wvb,
    unsigned short* __restrict__ qh, unsigned short* __restrict__ ql,
    unsigned short* __restrict__ kh, unsigned short* __restrict__ kl,
    unsigned short* __restrict__ vt)
{
    __shared__ __align__(16) short LB[24576];          // 48 KB (2 x 24KB)

    const int bt = blockIdx.x;
    const unsigned short *Ah, *Al, *Bh, *Bl;
    int seg, arow0;
    if (bt < 128)      { Ah = xqh; Al = xql; Bh = wqh; Bl = wql; arow0 = bt * 64;         seg = 0; }
    else if (bt < 160) { Ah = xkh; Al = xkl; Bh = wkh; Bl = wkl; arow0 = (bt - 128) * 64; seg = 1; }
    else               { Ah = xvb; Al = xvb; Bh = wvb; Bl = wvb; arow0 = (bt - 160) * 64; seg = 2; }
    const bool split = (seg != 2);

    const int tid  = threadIdx.x;
    const int lane = tid & 63, wv = tid >> 6;
    const int wc = wv * 32;                            // wave col slice
    const int j0 = blockIdx.y * 128;

    floatx4 acc[4][2];
#pragma unroll
    for (int i = 0; i < 4; i++)
#pragma unroll
        for (int j = 0; j < 2; j++) acc[i][j] = {0.f, 0.f, 0.f, 0.f};

    const int lrow = lane >> 2;
    const int lch  = (lane & 3) * 8;
    const int gra  = 16 * wv;                          // A wave row base
    const int grb  = 32 * wv;                          // B wave row base
    const long gA0 = (long)(arow0 + gra + lrow) * 512 + lch;
    const long gB0 = (long)(j0    + grb + lrow) * 512 + lch;

    const int fr = lane & 15, fq = (lane >> 4) * 8;

#define QKV_STAGE(d, k0) do {                                                 \
        short* bb = LB + (d) * 12288;                                         \
        gll16(Ah + gA0 + (k0),            bb + gra * 32);                     \
        gll16(Bh + gB0 + (k0),            bb + 4096 + grb * 32);              \
        gll16(Bh + gB0 + (k0) + 16 * 512, bb + 4096 + (grb + 16) * 32);       \
        if (split) {                                                          \
            gll16(Al + gA0 + (k0),            bb + 2048 + gra * 32);          \
            gll16(Bl + gB0 + (k0),            bb + 8192 + grb * 32);          \
            gll16(Bl + gB0 + (k0) + 16 * 512, bb + 8192 + (grb + 16) * 32);   \
        }                                                                     \
    } while (0)

    QKV_STAGE(0, 0);
    __syncthreads();                        // tile 0 ready

#pragma unroll 2
    for (int t = 0; t < 16; t++) {
        const int cur = t & 1;
        if (t < 15) QKV_STAGE(cur ^ 1, (t + 1) * 32);   // issue-early
        const short* base = LB + cur * 12288;
        short8 ah[4], bh[2];
#pragma unroll
        for (int i = 0; i < 4; i++)
            ah[i] = *(const short8*)&base[(i * 16 + fr) * 32 + fq];
#pragma unroll
        for (int j = 0; j < 2; j++)
            bh[j] = *(const short8*)&base[4096 + (wc + j * 16 + fr) * 32 + fq];
        if (split) {
            short8 al[4], bl[2];
#pragma unroll
            for (int i = 0; i < 4; i++)
                al[i] = *(const short8*)&base[2048 + (i * 16 + fr) * 32 + fq];
#pragma unroll
            for (int j = 0; j < 2; j++)
                bl[j] = *(const short8*)&base[8192 + (wc + j * 16 + fr) * 32 + fq];
#pragma unroll
            for (int i = 0; i < 4; i++)
#pragma unroll
                for (int j = 0; j < 2; j++) {
                    acc[i][j] = __builtin_amdgcn_mfma_f32_16x16x32_bf16(ah[i], bh[j], acc[i][j], 0, 0, 0);
                    acc[i][j] = __builtin_amdgcn_mfma_f32_16x16x32_bf16(ah[i], bl[j], acc[i][j], 0, 0, 0);
                    acc[i][j] = __builtin_amdgcn_mfma_f32_16x16x32_bf16(al[i], bh[j], acc[i][j], 0, 0, 0);
                }
        } else {
#pragma unroll
            for (int i = 0; i < 4; i++)
#pragma unroll
                for (int j = 0; j < 2; j++)
                    acc[i][j] = __builtin_amdgcn_mfma_f32_16x16x32_bf16(ah[i], bh[j], acc[i][j], 0, 0, 0);
        }
        __syncthreads();                    // drain-late: vmcnt after compute
    }
#undef QKV_STAGE

    const int cr = (lane >> 4) * 4, cc = lane & 15;
    if (seg == 2) {
        // LDS transpose: S2[c_local][k'_local], rows padded to 72 shorts
        short (*S2)[72] = (short(*)[72])LB;            // 128 x 72 = 18 KB
#pragma unroll
        for (int i = 0; i < 4; i++)
#pragma unroll
            for (int j = 0; j < 2; j++)
#pragma unroll
                for (int r = 0; r < 4; r++)
                    S2[wc + j * 16 + cc][i * 16 + cr + r] =
                        (short)f2bf(acc[i][j][r]);
        __syncthreads();
        const int orow = tid >> 1;            // c_local 0..127
        const int os   = (tid & 1) * 32;      // k'_local chunk
        unsigned short* dst = vt + (long)(arow0 >> 8) * 131072
                            + (long)(j0 + orow) * 256 + (arow0 & 255) + os;
#pragma unroll
        for (int c8 = 0; c8 < 4; c8++)
            *(short8*)(dst + c8 * 8) = *(const short8*)&S2[orow][os + c8 * 8];
    } else {
#pragma unroll
        for (int i = 0; i < 4; i++)
#pragma unroll
            for (int j = 0; j < 2; j++) {
                const int gj = j0 + wc + j * 16 + cc;
#pragma unroll
                for (int r = 0; r < 4; r++) {
                    const int gi = arow0 + i * 16 + cr + r;
                    const float v = acc[i][j][r];
                    const unsigned short h = f2bf(v);
                    const unsigned short lo = f2bf(v - bf2f(h));
                    if (seg == 0) {
                        const long orow = (long)((gi & 7) * 1024 + ((gi >> 3) & 15) * 64 + (gi >> 7));
                        qh[orow * 512 + gj] = h;
                        ql[orow * 512 + gj] = lo;
                    } else {
                        kh[(long)gi * 512 + gj] = h;
                        kl[(long)gi * 512 + gj] = lo;
                    }
                }
            }
    }
}

// ---------------------------------------------------------------------------
// sim GEMM, 64x64 tiles (512 blocks), bf16x3.  Round 14: gll_lds width-16
// dbuf issue-early/drain-late (one barrier/step), norms SELF-CONTAINED:
// row ssq accumulated from the MFMA fragments (4 lanes/row cover disjoint
// 8-elem chunks; xadd16+xadd32 completes the row sum). Wave-uniform
// predicates: waves 0,2 own A rows; waves 0,1 own B cols.
// Per buffer (shorts): Ash[64][32]@0, Asl@2048, Bsh@4096, Bsl@6144.
// ---------------------------------------------------------------------------
__global__ __launch_bounds__(256, 2) void gemm_sim64(
    const unsigned short* __restrict__ Ah, const unsigned short* __restrict__ Al,
    const unsigned short* __restrict__ Bh, const unsigned short* __restrict__ Bl,
    float* __restrict__ Out)
{
    const int z = blockIdx.z;
    Ah += (long)z * 131072;  Al += (long)z * 131072;
    Bh += (long)z * 524288;  Bl += (long)z * 524288;
    Out += (long)z * 262144;

    __shared__ __align__(16) short LB[16384];          // 32 KB (2 x 16KB)
    __shared__ float sRA[64];
    __shared__ float sRB[64];

    const int tid  = threadIdx.x;
    const int lane = tid & 63, wv = tid >> 6;
    const int wr = (wv >> 1) * 32, wc = (wv & 1) * 32;
    const int i0 = blockIdx.x * 64, j0 = blockIdx.y * 64;

    floatx4 acc[2][2];
#pragma unroll
    for (int i = 0; i < 2; i++)
#pragma unroll
        for (int j = 0; j < 2; j++) acc[i][j] = {0.f, 0.f, 0.f, 0.f};

    const int lrow = lane >> 2;
    const int lch  = (lane & 3) * 8;
    const int gr   = 16 * wv;                          // wave row base
    const long gA0 = (long)(i0 + gr + lrow) * 512 + lch;
    const long gB0 = (long)(j0 + gr + lrow) * 512 + lch;

    const int fr = lane & 15, fq = (lane >> 4) * 8;
    const bool doA = ((wv & 1) == 0);   // waves 0,2: A rows wr..wr+31
    const bool doB = (wv < 2);          // waves 0,1: B cols wc..wc+31

    float ssqA0 = 0.0f, ssqA1 = 0.0f, ssqB0 = 0.0f, ssqB1 = 0.0f;

#define SIM_STAGE(d, k0) do {                                                 \
        short* bb = LB + (d) * 8192;                                          \
        gll16(Ah + gA0 + (k0), bb + gr * 32);                                 \
        gll16(Al + gA0 + (k0), bb + 2048 + gr * 32);                          \
        gll16(Bh + gB0 + (k0), bb + 4096 + gr * 32);                          \
        gll16(Bl + gB0 + (k0), bb + 6144 + gr * 32);                          \
    } while (0)

    SIM_STAGE(0, 0);
    __syncthreads();

#pragma unroll 2
    for (int t = 0; t < 16; t++) {
        const int cur = t & 1;
        if (t < 15) SIM_STAGE(cur ^ 1, (t + 1) * 32);   // issue-early
        const short* base = LB + cur * 8192;
        short8 ah[2], al[2], bh[2], bl[2];
#pragma unroll
        for (int i = 0; i < 2; i++) {
            ah[i] = *(const short8*)&base[(wr + i * 16 + fr) * 32 + fq];
            al[i] = *(const short8*)&base[2048 + (wr + i * 16 + fr) * 32 + fq];
        }
#pragma unroll
        for (int j = 0; j < 2; j++) {
            bh[j] = *(const short8*)&base[4096 + (wc + j * 16 + fr) * 32 + fq];
            bl[j] = *(const short8*)&base[6144 + (wc + j * 16 + fr) * 32 + fq];
        }
        if (doA) {
#pragma unroll
            for (int e = 0; e < 8; e++) {
                const float v0 = bf2f((unsigned short)ah[0][e]) + bf2f((unsigned short)al[0][e]);
                const float v1 = bf2f((unsigned short)ah[1][e]) + bf2f((unsigned short)al[1][e]);
                ssqA0 = fmaf(v0, v0, ssqA0);
                ssqA1 = fmaf(v1, v1, ssqA1);
            }
        }
        if (doB) {
#pragma unroll
            for (int e = 0; e < 8; e++) {
                const float v0 = bf2f((unsigned short)bh[0][e]) + bf2f((unsigned short)bl[0][e]);
                const float v1 = bf2f((unsigned short)bh[1][e]) + bf2f((unsigned short)bl[1][e]);
                ssqB0 = fmaf(v0, v0, ssqB0);
                ssqB1 = fmaf(v1, v1, ssqB1);
            }
        }
#pragma unroll
        for (int i = 0; i < 2; i++)
#pragma unroll
            for (int j = 0; j < 2; j++) {
                acc[i][j] = __builtin_amdgcn_mfma_f32_16x16x32_bf16(ah[i], bh[j], acc[i][j], 0, 0, 0);
                acc[i][j] = __builtin_amdgcn_mfma_f32_16x16x32_bf16(ah[i], bl[j], acc[i][j], 0, 0, 0);
                acc[i][j] = __builtin_amdgcn_mfma_f32_16x16x32_bf16(al[i], bh[j], acc[i][j], 0, 0, 0);
            }
        __syncthreads();                    // drain-late
    }
#undef SIM_STAGE

    // complete row sums: the 4 lanes {fr, fr+16, fr+32, fr+48} hold disjoint
    // 8-elem partials of the same row -> xadd16 + xadd32 sums all four.
    if (doA) {
        ssqA0 = xadd32(xadd16(ssqA0));
        ssqA1 = xadd32(xadd16(ssqA1));
        if (lane < 16) {
            sRA[wr + lane]      = 1.0f / fmaxf(sqrtf(ssqA0), 1e-12f);
            sRA[wr + 16 + lane] = 1.0f / fmaxf(sqrtf(ssqA1), 1e-12f);
        }
    }
    if (doB) {
        ssqB0 = xadd32(xadd16(ssqB0));
        ssqB1 = xadd32(xadd16(ssqB1));
        if (lane < 16) {
            sRB[wc + lane]      = 1.0f / fmaxf(sqrtf(ssqB0), 1e-12f);
            sRB[wc + 16 + lane] = 1.0f / fmaxf(sqrtf(ssqB1), 1e-12f);
        }
    }
    __syncthreads();

    const int cr = (lane >> 4) * 4, cc = lane & 15;
#pragma unroll
    for (int i = 0; i < 2; i++)
#pragma unroll
        for (int j = 0; j < 2; j++) {
            const int lc = wc + j * 16 + cc;
            const float sq = sRB[lc];
            const int gj = j0 + lc;
#pragma unroll
            for (int r = 0; r < 4; r++) {
                const int lr = wr + i * 16 + cr + r;
                Out[(long)(i0 + lr) * 1024 + gj] = acc[i][j][r] * sRA[lr] * sq;
            }
        }
}

// ---------------------------------------------------------------------------
// Plain bf16 MFMA GEMM v2 (T@V and final proj): 64x128 tiles, BK=32,
// gll_lds width-16 dbuf, issue-early/drain-late 2-phase (verified r12).
// ---------------------------------------------------------------------------
template <bool BIAS, bool OPERM, bool OUT_BF16>
__global__ __launch_bounds__(256, 2) void gemm_bf16_v2(
    const unsigned short* __restrict__ A, const unsigned short* __restrict__ B,
    const float* __restrict__ bias, void* __restrict__ OutV,
    int Kdim, int lda, int ldb, int ldo, long sA, long sB, long sO)
{
    __shared__ __align__(16) short LB[12288];          // 24 KB (2 x 12KB)

    const int tid  = threadIdx.x;
    const int lane = tid & 63, wv = tid >> 6;
    const int wc = wv * 32;
    const int i0 = blockIdx.x * 64, j0 = blockIdx.y * 128;

    floatx4 acc[4][2];
#pragma unroll
    for (int i = 0; i < 4; i++)
#pragma unroll
        for (int j = 0; j < 2; j++) acc[i][j] = {0.f, 0.f, 0.f, 0.f};

    const unsigned short* pa = A + (long)blockIdx.z * sA;
    const unsigned short* pb = B + (long)blockIdx.z * sB;

    const int lrow = lane >> 2;
    const int lch  = (lane & 3) * 8;
    const int gra  = 16 * wv;                          // A wave row base
    const int grb  = 32 * wv;                          // B wave row base
    const long gA0 = (long)(i0 + gra + lrow) * lda + lch;
    const long gB0 = (long)(j0 + grb + lrow) * ldb + lch;

    const int fr = lane & 15, fq = (lane >> 4) * 8;

#define BF2_STAGE(d, k0) do {                                                 \
        short* bb = LB + (d) * 6144;                                          \
        gll16(pa + gA0 + (k0),             bb + gra * 32);                    \
        gll16(pb + gB0 + (k0),             bb + 2048 + grb * 32);             \
        gll16(pb + gB0 + (k0) + 16 * ldb,  bb + 2048 + (grb + 16) * 32);      \
    } while (0)

    const int nt = Kdim >> 5;
    BF2_STAGE(0, 0);
    __syncthreads();

#pragma unroll 2
    for (int t = 0; t < nt; t++) {
        const int cur = t & 1;
        if (t < nt - 1) BF2_STAGE(cur ^ 1, (t + 1) * 32);   // issue-early
        const short* base = LB + cur * 6144;
        short8 af[4], bf[2];
#pragma unroll
        for (int i = 0; i < 4; i++)
            af[i] = *(const short8*)&base[(i * 16 + fr) * 32 + fq];
#pragma unroll
        for (int j = 0; j < 2; j++)
            bf[j] = *(const short8*)&base[2048 + (wc + j * 16 + fr) * 32 + fq];
#pragma unroll
        for (int i = 0; i < 4; i++)
#pragma unroll
            for (int j = 0; j < 2; j++)
                acc[i][j] = __builtin_amdgcn_mfma_f32_16x16x32_bf16(af[i], bf[j], acc[i][j], 0, 0, 0);
        __syncthreads();                    // drain-late
    }
#undef BF2_STAGE

    float* Of = nullptr; unsigned short* Ob = nullptr;
    if constexpr (OUT_BF16) Ob = (unsigned short*)OutV + (long)blockIdx.z * sO;
    else                    Of = (float*)OutV + (long)blockIdx.z * sO;
    const int cr = (lane >> 4) * 4, cc = lane & 15;
#pragma unroll
    for (int i = 0; i < 4; i++) {
#pragma unroll
        for (int j = 0; j < 2; j++) {
            const int gj = j0 + wc + j * 16 + cc;
            float bb = 0.0f;
            if constexpr (BIAS) bb = bias[gj];
#pragma unroll
            for (int r = 0; r < 4; r++) {
                const int gi = i0 + i * 16 + cr + r;
                float v = acc[i][j][r] + bb;
                long idx;
                if constexpr (OPERM)
                    idx = (long)((gi & 63) * 128 + ((gi >> 6) & 15) * 8 + (gi >> 10)) * ldo + gj;
                else
                    idx = (long)gi * ldo + gj;
                if constexpr (OUT_BF16) Ob[idx] = f2bf(v);
                else                    Of[idx] = v;
            }
        }
    }
}

// ---------------------------------------------------------------------------
// Sinkhorn, rotated dual layouts + DPP + permlane butterflies + early exit.
// ---------------------------------------------------------------------------
__global__ __launch_bounds__(256, 2) void sinkhorn5(
    const float* __restrict__ sim, float* __restrict__ score,
    unsigned short* __restrict__ Tt)
{
    const int lane = threadIdx.x & 63;
    const int bk   = blockIdx.x * 4 + (threadIdx.x >> 6);
    const float* S = sim + (long)bk * 1024;
    const int m = lane & 15, g = lane >> 4;

    int idx[16];
    idx[0] = m;
    idx[1]  = RRI(m, 0x121); idx[2]  = RRI(m, 0x122); idx[3]  = RRI(m, 0x123);
    idx[4]  = RRI(m, 0x124); idx[5]  = RRI(m, 0x125); idx[6]  = RRI(m, 0x126);
    idx[7]  = RRI(m, 0x127); idx[8]  = RRI(m, 0x128); idx[9]  = RRI(m, 0x129);
    idx[10] = RRI(m, 0x12a); idx[11] = RRI(m, 0x12b); idx[12] = RRI(m, 0x12c);
    idx[13] = RRI(m, 0x12d); idx[14] = RRI(m, 0x12e); idx[15] = RRI(m, 0x12f);

    float K1[16], K2R[16], sv[16];
#pragma unroll
    for (int j = 0; j < 16; j++) {
        K1[j] = __expf((S[m * 64 + g * 16 + idx[j]] - 1.0f) * 20.0f);
        const float s_ = S[idx[j] * 64 + lane];
        sv[j]  = s_;
        K2R[j] = __expf((s_ - 1.0f) * 20.0f);
    }

    const float muP = 0.0625f + 1e-8f;
    const float nuP = 0.015625f + 1e-8f;
    float b = 1.0f;
    float aB[16], bB[16];
#pragma unroll
    for (int j = 0; j < 16; j++) bB[j] = 1.0f;

#pragma unroll 1
    for (int it = 0; it < 100; it++) {
        float s0 = 0, s1 = 0, s2 = 0, s3 = 0;
#pragma unroll
        for (int j = 0; j < 4; j++) {
            s0 = fmaf(K1[j],      bB[j],      s0);
            s1 = fmaf(K1[4 + j],  bB[4 + j],  s1);
            s2 = fmaf(K1[8 + j],  bB[8 + j],  s2);
            s3 = fmaf(K1[12 + j], bB[12 + j], s3);
        }
        float s = (s0 + s1) + (s2 + s3);
        s = xadd16(s);
        s = xadd32(s);
        const float a = muP * fastrcp(s);
        GATH16(aB, a);
        float t0 = 0, t1 = 0, t2 = 0, t3 = 0;
#pragma unroll
        for (int j = 0; j < 4; j++) {
            t0 = fmaf(K2R[j],      aB[j],      t0);
            t1 = fmaf(K2R[4 + j],  aB[4 + j],  t1);
            t2 = fmaf(K2R[8 + j],  aB[8 + j],  t2);
            t3 = fmaf(K2R[12 + j], aB[12 + j], t3);
        }
        const float bp_ = b;
        b = nuP * fastrcp((t0 + t1) + (t2 + t3));
        GATH16(bB, b);
        const int conv = __builtin_fabsf(b - bp_) <= 1e-5f * __builtin_fabsf(b);
        if (__all(conv)) break;
    }

    float* Sc = score + (long)bk * 1024;
    unsigned short* Tp = Tt + (long)(bk >> 8) * 262144 + (bk & 255);
#pragma unroll
    for (int j = 0; j < 16; j++) {
        const int row = idx[j];
        const float Tv = aB[j] * K2R[j] * b;
        Sc[row * 64 + lane] = 1024.0f * sv[j] * Tv;
        Tp[(long)(row * 64 + lane) * 256] = f2bf(Tv);
    }
}

extern "C" void kernel_launch(void* const* d_in, const int* in_sizes, int n_in,
                              void* d_out, int out_size, void* d_ws, size_t ws_size,
                              hipStream_t stream)
{
    (void)in_sizes; (void)n_in; (void)out_size; (void)ws_size;
    const float* xq = (const float*)d_in[0];
    const float* xk = (const float*)d_in[1];
    const float* xv = (const float*)d_in[2];
    const float* Wq = (const float*)d_in[3];
    const float* Wk = (const float*)d_in[4];
    const float* Wv = (const float*)d_in[5];
    const float* Wp = (const float*)d_in[6];
    const float* bp = (const float*)d_in[7];

    float* out_x     = (float*)d_out;           // (Nq,M,B,C) = 8192 x 512
    float* out_score = out_x + 8192L * 512;     // (B,K,M,Nq) = 2048 x 1024

    // workspace (47 MB of the proven 48 MB); regions reused across phases
    char* W = (char*)d_ws;
    const long MB = 1 << 20;
    unsigned short* qh   = (unsigned short*)(W + 0);        // 8MB [b][mn][c]
    unsigned short* ql   = (unsigned short*)(W + 8 * MB);   // 8MB
    unsigned short* xq_h = (unsigned short*)(W + 16 * MB);  // 8MB, dead after qkv
    float*          simb = (float*)(W + 16 * MB);           // 8MB (reuse)
    unsigned short* xq_l = (unsigned short*)(W + 24 * MB);  // 8MB, dead after qkv
    unsigned short* xpre = (unsigned short*)(W + 24 * MB);  // 8MB (reuse)
    unsigned short* xk_h = (unsigned short*)(W + 32 * MB);  // 2MB, dead after qkv
    unsigned short* xk_l = (unsigned short*)(W + 34 * MB);  // 2MB
    unsigned short* Tt   = (unsigned short*)(W + 32 * MB);  // 4MB (reuse)
    unsigned short* xv_b = (unsigned short*)(W + 36 * MB);  // 2MB
    unsigned short* kh   = (unsigned short*)(W + 38 * MB);  // 2MB [b][k'][c]
    unsigned short* kl   = (unsigned short*)(W + 40 * MB);  // 2MB
    unsigned short* vt   = (unsigned short*)(W + 42 * MB);  // 2MB [b][c][k']
    unsigned short* wqh  = (unsigned short*)(W + 44 * MB);
    unsigned short* wql  = (unsigned short*)(W + 44 * MB + 1 * 524288);
    unsigned short* wkh  = (unsigned short*)(W + 44 * MB + 2 * 524288);
    unsigned short* wkl  = (unsigned short*)(W + 44 * MB + 3 * 524288);
    unsigned short* wvb  = (unsigned short*)(W + 44 * MB + 4 * 524288);
    unsigned short* wpb  = (unsigned short*)(W + 44 * MB + 5 * 524288);

    const dim3 blk(256);

    // 1: precast/split all fp32 operands (memory-bound, one dispatch)
    prep<<<7168, blk, 0, stream>>>(xq, xk, xv, Wq, Wk, Wv, Wp,
                                   xq_h, xq_l, xk_h, xk_l, xv_b,
                                   wqh, wql, wkh, wkl, wvb, wpb);

    // 2: fused q/k/v projections (64x128 tiles, 3/CU, gll_lds dbuf)
    gemm_qkv2<<<dim3(192, 4), blk, 0, stream>>>(
        xq_h, xq_l, xk_h, xk_l, xv_b, wqh, wql, wkh, wkl, wvb,
        qh, ql, kh, kl, vt);

    // 3: sim[b][k'][mn] = (k.q) * rs_k * rs_q  (gll_lds dbuf, norms from
    //    MFMA fragments — self-contained)
    gemm_sim64<<<dim3(4, 16, 8), blk, 0, stream>>>(
        (const unsigned short*)kh, (const unsigned short*)kl,
        (const unsigned short*)qh, (const unsigned short*)ql,
        simb);

    // 4: Sinkhorn -> score (out) + T bf16 [b][mn][k']
    sinkhorn5<<<512, blk, 0, stream>>>(simb, out_score, Tt);

    // 5: xpre[b][mn][c] = sum_k' T[b][mn][k'] * v[b][k'][c]
    gemm_bf16_v2<false, false, true><<<dim3(16, 4, 8), blk, 0, stream>>>(
        Tt, vt, nullptr, xpre,
        256, 256, 256, 512, 262144, 131072, 524288);

    // 6: x = xpre @ Wp^T + bp, rows (b,mn)->(n,m,b), fp32 out
    gemm_bf16_v2<true, true, false><<<dim3(128, 4), blk, 0, stream>>>(
        xpre, wpb, bp, out_x,
        512, 512, 512, 512, 0, 0, 0);
}

// Round 10
// 176.009 us; speedup vs baseline: 1.0534x; 1.0171x over previous
//
#include <hip/hip_runtime.h>

// ---------------------------------------------------------------------------
// AttentionOT  (Nq=64, M=16, B=8, K=256, C=512)
//   Front (error-critical, feeds exp(20*sim)): bf16x3 split MFMA (Markidis),
//     operands PRE-SPLIT by a memory-bound prep pass.
//   Back half: plain bf16 MFMA, weights precast.
//   Sinkhorn: launch_bounds(256,2), permlane16/32 butterflies, early exit
//     (round 15: tol 1e-4 — geometric convergence, error ≪ 2^-7 budget).
//   qkv GEMM (r10-11): 64x128 tiles, gll_lds width-16 dbuf, issue-early/
//     drain-late 2-phase, 768 blocks = 3/CU.
//   sim64 (r14): same schedule + self-contained fragment norms.
//     Round 15: XCD-chunked block swizzle — one complete batch z per XCD
//     (lin&7 = XCD under round-robin dispatch), per-XCD working set
//     k[z]+q[z] ~5MB ≈ L2-resident instead of all-batch thrash.
//   Back GEMMs (r12): same schedule, 512 blocks = 2/CU.
//   6 dispatches: prep -> qkv -> sim -> sinkhorn -> T@V -> proj.
// ---------------------------------------------------------------------------

typedef short   short8  __attribute__((ext_vector_type(8)));
typedef float   floatx4 __attribute__((ext_vector_type(4)));
typedef unsigned int uint2e __attribute__((ext_vector_type(2)));

static __device__ __forceinline__ float fastrcp(float x) {
    return __builtin_amdgcn_rcpf(x);
}
static __device__ __forceinline__ unsigned short f2bf(float f) {
    union { float f; unsigned u; } c; c.f = f;
    unsigned r = c.u + 0x7FFF + ((c.u >> 16) & 1);   // RNE
    return (unsigned short)(r >> 16);
}
static __device__ __forceinline__ float bf2f(unsigned short h) {
    union { unsigned u; float f; } c; c.u = (unsigned)h << 16;
    return c.f;
}

// HBM -> LDS direct DMA, 16B per lane. LDS dest is wave-uniform base;
// HW writes lane i at base + i*16 (m03/m97/m104).
static __device__ __forceinline__ void gll16(const unsigned short* g, short* l) {
    __builtin_amdgcn_global_load_lds(
        (const __attribute__((address_space(1))) void*)g,
        (__attribute__((address_space(3))) void*)l, 16, 0, 0);
}

// Cross-lane butterfly adds via gfx950 permlane16/32_swap.
#if __has_builtin(__builtin_amdgcn_permlane16_swap)
static __device__ __forceinline__ float xadd16(float s) {
    uint2e r = __builtin_amdgcn_permlane16_swap(
        __float_as_uint(s), __float_as_uint(s), false, false);
    return __uint_as_float(r.x) + __uint_as_float(r.y);
}
#else
static __device__ __forceinline__ float xadd16(float s) {
    return s + __shfl_xor(s, 16, 64);
}
#endif
#if __has_builtin(__builtin_amdgcn_permlane32_swap)
static __device__ __forceinline__ float xadd32(float s) {
    uint2e r = __builtin_amdgcn_permlane32_swap(
        __float_as_uint(s), __float_as_uint(s), false, false);
    return __uint_as_float(r.x) + __uint_as_float(r.y);
}
#else
static __device__ __forceinline__ float xadd32(float s) {
    return s + __shfl_xor(s, 32, 64);
}
#endif

#define RRI(x, C) __builtin_amdgcn_update_dpp(0, (x), (C), 0xf, 0xf, true)
#define RRF(x, C) __int_as_float(RRI(__float_as_int(x), (C)))
#define GATH16(d, s) do { d[0] = (s);                                        \
    d[1]  = RRF((s), 0x121); d[2]  = RRF((s), 0x122);                        \
    d[3]  = RRF((s), 0x123); d[4]  = RRF((s), 0x124);                        \
    d[5]  = RRF((s), 0x125); d[6]  = RRF((s), 0x126);                        \
    d[7]  = RRF((s), 0x127); d[8]  = RRF((s), 0x128);                        \
    d[9]  = RRF((s), 0x129); d[10] = RRF((s), 0x12a);                        \
    d[11] = RRF((s), 0x12b); d[12] = RRF((s), 0x12c);                        \
    d[13] = RRF((s), 0x12d); d[14] = RRF((s), 0x12e);                        \
    d[15] = RRF((s), 0x12f); } while (0)

// ---------------------------------------------------------------------------
// prep: fp32 -> bf16 split (xq,xk,Wq,Wk) / cast (xv,Wv,Wp).
// ---------------------------------------------------------------------------
__global__ __launch_bounds__(256) void prep(
    const float* __restrict__ xq, const float* __restrict__ xk,
    const float* __restrict__ xv, const float* __restrict__ Wq,
    const float* __restrict__ Wk, const float* __restrict__ Wv,
    const float* __restrict__ Wp,
    unsigned short* __restrict__ xqh, unsigned short* __restrict__ xql,
    unsigned short* __restrict__ xkh, unsigned short* __restrict__ xkl,
    unsigned short* __restrict__ xvb,
    unsigned short* __restrict__ wqh, unsigned short* __restrict__ wql,
    unsigned short* __restrict__ wkh, unsigned short* __restrict__ wkl,
    unsigned short* __restrict__ wvb, unsigned short* __restrict__ wpb)
{
    const int b = blockIdx.x;
    const float* src; unsigned short *dh, *dl; long base;
    if (b < 4096)      { src = xq; dh = xqh; dl = xql;     base = (long)b * 256; }
    else if (b < 5120) { src = xk; dh = xkh; dl = xkl;     base = (long)(b - 4096) * 256; }
    else if (b < 6144) { src = xv; dh = xvb; dl = nullptr; base = (long)(b - 5120) * 256; }
    else if (b < 6400) { src = Wq; dh = wqh; dl = wql;     base = (long)(b - 6144) * 256; }
    else if (b < 6656) { src = Wk; dh = wkh; dl = wkl;     base = (long)(b - 6400) * 256; }
    else if (b < 6912) { src = Wv; dh = wvb; dl = nullptr; base = (long)(b - 6656) * 256; }
    else               { src = Wp; dh = wpb; dl = nullptr; base = (long)(b - 6912) * 256; }
    const long i = base + threadIdx.x;
    float4 v = ((const float4*)src)[i];
    ushort4 h;
    h.x = f2bf(v.x); h.y = f2bf(v.y); h.z = f2bf(v.z); h.w = f2bf(v.w);
    ((ushort4*)dh)[i] = h;
    if (dl) {
        ushort4 l;
        l.x = f2bf(v.x - bf2f(h.x)); l.y = f2bf(v.y - bf2f(h.y));
        l.z = f2bf(v.z - bf2f(h.z)); l.w = f2bf(v.w - bf2f(h.w));
        ((ushort4*)dl)[i] = l;
    }
}

// ---------------------------------------------------------------------------
// Fused q/k/v projection.  64x128 tiles, BK=32, 768 blocks (3/CU).
// gll_lds dbuf 2-phase (verified r10-11).
// ---------------------------------------------------------------------------
__global__ __launch_bounds__(256, 3) void gemm_qkv2(
    const unsigned short* __restrict__ xqh, const unsigned short* __restrict__ xql,
    const unsigned short* __restrict__ xkh, const unsigned short* __restrict__ xkl,
    const unsigned short* __restrict__ xvb,
    const unsigned short* __restrict__ wqh, const unsigned short* __restrict__ wql,
    const unsigned short* __restrict__ wkh, const unsigned short* __restrict__ wkl,
    const unsigned short* __restrict__ wvb,
    unsigned short* __restrict__ qh, unsigned short* __restrict__ ql,
    unsigned short* __restrict__ kh, unsigned short* __restrict__ kl,
    unsigned short* __restrict__ vt)
{
    __shared__ __align__(16) short LB[24576];          // 48 KB (2 x 24KB)

    const int bt = blockIdx.x;
    const unsigned short *Ah, *Al, *Bh, *Bl;
    int seg, arow0;
    if (bt < 128)      { Ah = xqh; Al = xql; Bh = wqh; Bl = wql; arow0 = bt * 64;         seg = 0; }
    else if (bt < 160) { Ah = xkh; Al = xkl; Bh = wkh; Bl = wkl; arow0 = (bt - 128) * 64; seg = 1; }
    else               { Ah = xvb; Al = xvb; Bh = wvb; Bl = wvb; arow0 = (bt - 160) * 64; seg = 2; }
    const bool split = (seg != 2);

    const int tid  = threadIdx.x;
    const int lane = tid & 63, wv = tid >> 6;
    const int wc = wv * 32;                            // wave col slice
    const int j0 = blockIdx.y * 128;

    floatx4 acc[4][2];
#pragma unroll
    for (int i = 0; i < 4; i++)
#pragma unroll
        for (int j = 0; j < 2; j++) acc[i][j] = {0.f, 0.f, 0.f, 0.f};

    const int lrow = lane >> 2;
    const int lch  = (lane & 3) * 8;
    const int gra  = 16 * wv;                          // A wave row base
    const int grb  = 32 * wv;                          // B wave row base
    const long gA0 = (long)(arow0 + gra + lrow) * 512 + lch;
    const long gB0 = (long)(j0    + grb + lrow) * 512 + lch;

    const int fr = lane & 15, fq = (lane >> 4) * 8;

#define QKV_STAGE(d, k0) do {                                                 \
        short* bb = LB + (d) * 12288;                                         \
        gll16(Ah + gA0 + (k0),            bb + gra * 32);                     \
        gll16(Bh + gB0 + (k0),            bb + 4096 + grb * 32);              \
        gll16(Bh + gB0 + (k0) + 16 * 512, bb + 4096 + (grb + 16) * 32);       \
        if (split) {                                                          \
            gll16(Al + gA0 + (k0),            bb + 2048 + gra * 32);          \
            gll16(Bl + gB0 + (k0),            bb + 8192 + grb * 32);          \
            gll16(Bl + gB0 + (k0) + 16 * 512, bb + 8192 + (grb + 16) * 32);   \
        }                                                                     \
    } while (0)

    QKV_STAGE(0, 0);
    __syncthreads();                        // tile 0 ready

#pragma unroll 2
    for (int t = 0; t < 16; t++) {
        const int cur = t & 1;
        if (t < 15) QKV_STAGE(cur ^ 1, (t + 1) * 32);   // issue-early
        const short* base = LB + cur * 12288;
        short8 ah[4], bh[2];
#pragma unroll
        for (int i = 0; i < 4; i++)
            ah[i] = *(const short8*)&base[(i * 16 + fr) * 32 + fq];
#pragma unroll
        for (int j = 0; j < 2; j++)
            bh[j] = *(const short8*)&base[4096 + (wc + j * 16 + fr) * 32 + fq];
        if (split) {
            short8 al[4], bl[2];
#pragma unroll
            for (int i = 0; i < 4; i++)
                al[i] = *(const short8*)&base[2048 + (i * 16 + fr) * 32 + fq];
#pragma unroll
            for (int j = 0; j < 2; j++)
                bl[j] = *(const short8*)&base[8192 + (wc + j * 16 + fr) * 32 + fq];
#pragma unroll
            for (int i = 0; i < 4; i++)
#pragma unroll
                for (int j = 0; j < 2; j++) {
                    acc[i][j] = __builtin_amdgcn_mfma_f32_16x16x32_bf16(ah[i], bh[j], acc[i][j], 0, 0, 0);
                    acc[i][j] = __builtin_amdgcn_mfma_f32_16x16x32_bf16(ah[i], bl[j], acc[i][j], 0, 0, 0);
                    acc[i][j] = __builtin_amdgcn_mfma_f32_16x16x32_bf16(al[i], bh[j], acc[i][j], 0, 0, 0);
                }
        } else {
#pragma unroll
            for (int i = 0; i < 4; i++)
#pragma unroll
                for (int j = 0; j < 2; j++)
                    acc[i][j] = __builtin_amdgcn_mfma_f32_16x16x32_bf16(ah[i], bh[j], acc[i][j], 0, 0, 0);
        }
        __syncthreads();                    // drain-late: vmcnt after compute
    }
#undef QKV_STAGE

    const int cr = (lane >> 4) * 4, cc = lane & 15;
    if (seg == 2) {
        // LDS transpose: S2[c_local][k'_local], rows padded to 72 shorts
        short (*S2)[72] = (short(*)[72])LB;            // 128 x 72 = 18 KB
#pragma unroll
        for (int i = 0; i < 4; i++)
#pragma unroll
            for (int j = 0; j < 2; j++)
#pragma unroll
                for (int r = 0; r < 4; r++)
                    S2[wc + j * 16 + cc][i * 16 + cr + r] =
                        (short)f2bf(acc[i][j][r]);
        __syncthreads();
        const int orow = tid >> 1;            // c_local 0..127
        const int os   = (tid & 1) * 32;      // k'_local chunk
        unsigned short* dst = vt + (long)(arow0 >> 8) * 131072
                            + (long)(j0 + orow) * 256 + (arow0 & 255) + os;
#pragma unroll
        for (int c8 = 0; c8 < 4; c8++)
            *(short8*)(dst + c8 * 8) = *(const short8*)&S2[orow][os + c8 * 8];
    } else {
#pragma unroll
        for (int i = 0; i < 4; i++)
#pragma unroll
            for (int j = 0; j < 2; j++) {
                const int gj = j0 + wc + j * 16 + cc;
#pragma unroll
                for (int r = 0; r < 4; r++) {
                    const int gi = arow0 + i * 16 + cr + r;
                    const float v = acc[i][j][r];
                    const unsigned short h = f2bf(v);
                    const unsigned short lo = f2bf(v - bf2f(h));
                    if (seg == 0) {
                        const long orow = (long)((gi & 7) * 1024 + ((gi >> 3) & 15) * 64 + (gi >> 7));
                        qh[orow * 512 + gj] = h;
                        ql[orow * 512 + gj] = lo;
                    } else {
                        kh[(long)gi * 512 + gj] = h;
                        kl[(long)gi * 512 + gj] = lo;
                    }
                }
            }
    }
}

// ---------------------------------------------------------------------------
// sim GEMM, 64x64 tiles (512 blocks), bf16x3, gll_lds dbuf, self-contained
// fragment norms (verified r14).  Round 15: XCD-chunked swizzle — under
// round-robin dispatch (XCD = linear_id & 7), remap so each XCD owns one
// complete batch z: per-XCD working set k[z]+q[z] ~5MB ≈ L2-resident.
// Bijective: 512 blocks = 8 XCD x 64 rank; (i0,j0) from rank.
// ---------------------------------------------------------------------------
__global__ __launch_bounds__(256, 2) void gemm_sim64(
    const unsigned short* __restrict__ Ah, const unsigned short* __restrict__ Al,
    const unsigned short* __restrict__ Bh, const unsigned short* __restrict__ Bl,
    float* __restrict__ Out)
{
    // XCD-chunked decode: lin = x + 4y + 64z (x fastest in dispatch order)
    const int lin  = blockIdx.x + 4 * blockIdx.y + 64 * blockIdx.z;
    const int z    = lin & 7;                 // XCD under %8 round-robin
    const int rank = lin >> 3;                // 0..63 within XCD
    const int i0 = (rank & 3) * 64;           // k' tile
    const int j0 = (rank >> 2) * 64;          // mn tile

    Ah += (long)z * 131072;  Al += (long)z * 131072;
    Bh += (long)z * 524288;  Bl += (long)z * 524288;
    Out += (long)z * 262144;

    __shared__ __align__(16) short LB[16384];          // 32 KB (2 x 16KB)
    __shared__ float sRA[64];
    __shared__ float sRB[64];

    const int tid  = threadIdx.x;
    const int lane = tid & 63, wv = tid >> 6;
    const int wr = (wv >> 1) * 32, wc = (wv & 1) * 32;

    floatx4 acc[2][2];
#pragma unroll
    for (int i = 0; i < 2; i++)
#pragma unroll
        for (int j = 0; j < 2; j++) acc[i][j] = {0.f, 0.f, 0.f, 0.f};

    const int lrow = lane >> 2;
    const int lch  = (lane & 3) * 8;
    const int gr   = 16 * wv;                          // wave row base
    const long gA0 = (long)(i0 + gr + lrow) * 512 + lch;
    const long gB0 = (long)(j0 + gr + lrow) * 512 + lch;

    const int fr = lane & 15, fq = (lane >> 4) * 8;
    const bool doA = ((wv & 1) == 0);   // waves 0,2: A rows wr..wr+31
    const bool doB = (wv < 2);          // waves 0,1: B cols wc..wc+31

    float ssqA0 = 0.0f, ssqA1 = 0.0f, ssqB0 = 0.0f, ssqB1 = 0.0f;

#define SIM_STAGE(d, k0) do {                                                 \
        short* bb = LB + (d) * 8192;                                          \
        gll16(Ah + gA0 + (k0), bb + gr * 32);                                 \
        gll16(Al + gA0 + (k0), bb + 2048 + gr * 32);                          \
        gll16(Bh + gB0 + (k0), bb + 4096 + gr * 32);                          \
        gll16(Bl + gB0 + (k0), bb + 6144 + gr * 32);                          \
    } while (0)

    SIM_STAGE(0, 0);
    __syncthreads();

#pragma unroll 2
    for (int t = 0; t < 16; t++) {
        const int cur = t & 1;
        if (t < 15) SIM_STAGE(cur ^ 1, (t + 1) * 32);   // issue-early
        const short* base = LB + cur * 8192;
        short8 ah[2], al[2], bh[2], bl[2];
#pragma unroll
        for (int i = 0; i < 2; i++) {
            ah[i] = *(const short8*)&base[(wr + i * 16 + fr) * 32 + fq];
            al[i] = *(const short8*)&base[2048 + (wr + i * 16 + fr) * 32 + fq];
        }
#pragma unroll
        for (int j = 0; j < 2; j++) {
            bh[j] = *(const short8*)&base[4096 + (wc + j * 16 + fr) * 32 + fq];
            bl[j] = *(const short8*)&base[6144 + (wc + j * 16 + fr) * 32 + fq];
        }
        if (doA) {
#pragma unroll
            for (int e = 0; e < 8; e++) {
                const float v0 = bf2f((unsigned short)ah[0][e]) + bf2f((unsigned short)al[0][e]);
                const float v1 = bf2f((unsigned short)ah[1][e]) + bf2f((unsigned short)al[1][e]);
                ssqA0 = fmaf(v0, v0, ssqA0);
                ssqA1 = fmaf(v1, v1, ssqA1);
            }
        }
        if (doB) {
#pragma unroll
            for (int e = 0; e < 8; e++) {
                const float v0 = bf2f((unsigned short)bh[0][e]) + bf2f((unsigned short)bl[0][e]);
                const float v1 = bf2f((unsigned short)bh[1][e]) + bf2f((unsigned short)bl[1][e]);
                ssqB0 = fmaf(v0, v0, ssqB0);
                ssqB1 = fmaf(v1, v1, ssqB1);
            }
        }
#pragma unroll
        for (int i = 0; i < 2; i++)
#pragma unroll
            for (int j = 0; j < 2; j++) {
                acc[i][j] = __builtin_amdgcn_mfma_f32_16x16x32_bf16(ah[i], bh[j], acc[i][j], 0, 0, 0);
                acc[i][j] = __builtin_amdgcn_mfma_f32_16x16x32_bf16(ah[i], bl[j], acc[i][j], 0, 0, 0);
                acc[i][j] = __builtin_amdgcn_mfma_f32_16x16x32_bf16(al[i], bh[j], acc[i][j], 0, 0, 0);
            }
        __syncthreads();                    // drain-late
    }
#undef SIM_STAGE

    if (doA) {
        ssqA0 = xadd32(xadd16(ssqA0));
        ssqA1 = xadd32(xadd16(ssqA1));
        if (lane < 16) {
            sRA[wr + lane]      = 1.0f / fmaxf(sqrtf(ssqA0), 1e-12f);
            sRA[wr + 16 + lane] = 1.0f / fmaxf(sqrtf(ssqA1), 1e-12f);
        }
    }
    if (doB) {
        ssqB0 = xadd32(xadd16(ssqB0));
        ssqB1 = xadd32(xadd16(ssqB1));
        if (lane < 16) {
            sRB[wc + lane]      = 1.0f / fmaxf(sqrtf(ssqB0), 1e-12f);
            sRB[wc + 16 + lane] = 1.0f / fmaxf(sqrtf(ssqB1), 1e-12f);
        }
    }
    __syncthreads();

    const int cr = (lane >> 4) * 4, cc = lane & 15;
#pragma unroll
    for (int i = 0; i < 2; i++)
#pragma unroll
        for (int j = 0; j < 2; j++) {
            const int lc = wc + j * 16 + cc;
            const float sq = sRB[lc];
            const int gj = j0 + lc;
#pragma unroll
            for (int r = 0; r < 4; r++) {
                const int lr = wr + i * 16 + cr + r;
                Out[(long)(i0 + lr) * 1024 + gj] = acc[i][j][r] * sRA[lr] * sq;
            }
        }
}

// ---------------------------------------------------------------------------
// Plain bf16 MFMA GEMM v2 (T@V and final proj): 64x128 tiles, BK=32,
// gll_lds width-16 dbuf, issue-early/drain-late 2-phase (verified r12).
// ---------------------------------------------------------------------------
template <bool BIAS, bool OPERM, bool OUT_BF16>
__global__ __launch_bounds__(256, 2) void gemm_bf16_v2(
    const unsigned short* __restrict__ A, const unsigned short* __restrict__ B,
    const float* __restrict__ bias, void* __restrict__ OutV,
    int Kdim, int lda, int ldb, int ldo, long sA, long sB, long sO)
{
    __shared__ __align__(16) short LB[12288];          // 24 KB (2 x 12KB)

    const int tid  = threadIdx.x;
    const int lane = tid & 63, wv = tid >> 6;
    const int wc = wv * 32;
    const int i0 = blockIdx.x * 64, j0 = blockIdx.y * 128;

    floatx4 acc[4][2];
#pragma unroll
    for (int i = 0; i < 4; i++)
#pragma unroll
        for (int j = 0; j < 2; j++) acc[i][j] = {0.f, 0.f, 0.f, 0.f};

    const unsigned short* pa = A + (long)blockIdx.z * sA;
    const unsigned short* pb = B + (long)blockIdx.z * sB;

    const int lrow = lane >> 2;
    const int lch  = (lane & 3) * 8;
    const int gra  = 16 * wv;                          // A wave row base
    const int grb  = 32 * wv;                          // B wave row base
    const long gA0 = (long)(i0 + gra + lrow) * lda + lch;
    const long gB0 = (long)(j0 + grb + lrow) * ldb + lch;

    const int fr = lane & 15, fq = (lane >> 4) * 8;

#define BF2_STAGE(d, k0) do {                                                 \
        short* bb = LB + (d) * 6144;                                          \
        gll16(pa + gA0 + (k0),             bb + gra * 32);                    \
        gll16(pb + gB0 + (k0),             bb + 2048 + grb * 32);             \
        gll16(pb + gB0 + (k0) + 16 * ldb,  bb + 2048 + (grb + 16) * 32);      \
    } while (0)

    const int nt = Kdim >> 5;
    BF2_STAGE(0, 0);
    __syncthreads();

#pragma unroll 2
    for (int t = 0; t < nt; t++) {
        const int cur = t & 1;
        if (t < nt - 1) BF2_STAGE(cur ^ 1, (t + 1) * 32);   // issue-early
        const short* base = LB + cur * 6144;
        short8 af[4], bf[2];
#pragma unroll
        for (int i = 0; i < 4; i++)
            af[i] = *(const short8*)&base[(i * 16 + fr) * 32 + fq];
#pragma unroll
        for (int j = 0; j < 2; j++)
            bf[j] = *(const short8*)&base[2048 + (wc + j * 16 + fr) * 32 + fq];
#pragma unroll
        for (int i = 0; i < 4; i++)
#pragma unroll
            for (int j = 0; j < 2; j++)
                acc[i][j] = __builtin_amdgcn_mfma_f32_16x16x32_bf16(af[i], bf[j], acc[i][j], 0, 0, 0);
        __syncthreads();                    // drain-late
    }
#undef BF2_STAGE

    float* Of = nullptr; unsigned short* Ob = nullptr;
    if constexpr (OUT_BF16) Ob = (unsigned short*)OutV + (long)blockIdx.z * sO;
    else                    Of = (float*)OutV + (long)blockIdx.z * sO;
    const int cr = (lane >> 4) * 4, cc = lane & 15;
#pragma unroll
    for (int i = 0; i < 4; i++) {
#pragma unroll
        for (int j = 0; j < 2; j++) {
            const int gj = j0 + wc + j * 16 + cc;
            float bb = 0.0f;
            if constexpr (BIAS) bb = bias[gj];
#pragma unroll
            for (int r = 0; r < 4; r++) {
                const int gi = i0 + i * 16 + cr + r;
                float v = acc[i][j][r] + bb;
                long idx;
                if constexpr (OPERM)
                    idx = (long)((gi & 63) * 128 + ((gi >> 6) & 15) * 8 + (gi >> 10)) * ldo + gj;
                else
                    idx = (long)gi * ldo + gj;
                if constexpr (OUT_BF16) Ob[idx] = f2bf(v);
                else                    Of[idx] = v;
            }
        }
    }
}

// ---------------------------------------------------------------------------
// Sinkhorn, rotated dual layouts + DPP + permlane butterflies + early exit
// (tol 1e-4, round 15).
// ---------------------------------------------------------------------------
__global__ __launch_bounds__(256, 2) void sinkhorn5(
    const float* __restrict__ sim, float* __restrict__ score,
    unsigned short* __restrict__ Tt)
{
    const int lane = threadIdx.x & 63;
    const int bk   = blockIdx.x * 4 + (threadIdx.x >> 6);
    const float* S = sim + (long)bk * 1024;
    const int m = lane & 15, g = lane >> 4;

    int idx[16];
    idx[0] = m;
    idx[1]  = RRI(m, 0x121); idx[2]  = RRI(m, 0x122); idx[3]  = RRI(m, 0x123);
    idx[4]  = RRI(m, 0x124); idx[5]  = RRI(m, 0x125); idx[6]  = RRI(m, 0x126);
    idx[7]  = RRI(m, 0x127); idx[8]  = RRI(m, 0x128); idx[9]  = RRI(m, 0x129);
    idx[10] = RRI(m, 0x12a); idx[11] = RRI(m, 0x12b); idx[12] = RRI(m, 0x12c);
    idx[13] = RRI(m, 0x12d); idx[14] = RRI(m, 0x12e); idx[15] = RRI(m, 0x12f);

    float K1[16], K2R[16], sv[16];
#pragma unroll
    for (int j = 0; j < 16; j++) {
        K1[j] = __expf((S[m * 64 + g * 16 + idx[j]] - 1.0f) * 20.0f);
        const float s_ = S[idx[j] * 64 + lane];
        sv[j]  = s_;
        K2R[j] = __expf((s_ - 1.0f) * 20.0f);
    }

    const float muP = 0.0625f + 1e-8f;
    const float nuP = 0.015625f + 1e-8f;
    float b = 1.0f;
    float aB[16], bB[16];
#pragma unroll
    for (int j = 0; j < 16; j++) bB[j] = 1.0f;

#pragma unroll 1
    for (int it = 0; it < 100; it++) {
        float s0 = 0, s1 = 0, s2 = 0, s3 = 0;
#pragma unroll
        for (int j = 0; j < 4; j++) {
            s0 = fmaf(K1[j],      bB[j],      s0);
            s1 = fmaf(K1[4 + j],  bB[4 + j],  s1);
            s2 = fmaf(K1[8 + j],  bB[8 + j],  s2);
            s3 = fmaf(K1[12 + j], bB[12 + j], s3);
        }
        float s = (s0 + s1) + (s2 + s3);
        s = xadd16(s);
        s = xadd32(s);
        const float a = muP * fastrcp(s);
        GATH16(aB, a);
        float t0 = 0, t1 = 0, t2 = 0, t3 = 0;
#pragma unroll
        for (int j = 0; j < 4; j++) {
            t0 = fmaf(K2R[j],      aB[j],      t0);
            t1 = fmaf(K2R[4 + j],  aB[4 + j],  t1);
            t2 = fmaf(K2R[8 + j],  aB[8 + j],  t2);
            t3 = fmaf(K2R[12 + j], aB[12 + j], t3);
        }
        const float bp_ = b;
        b = nuP * fastrcp((t0 + t1) + (t2 + t3));
        GATH16(bB, b);
        const int conv = __builtin_fabsf(b - bp_) <= 1e-4f * __builtin_fabsf(b);
        if (__all(conv)) break;
    }

    float* Sc = score + (long)bk * 1024;
    unsigned short* Tp = Tt + (long)(bk >> 8) * 262144 + (bk & 255);
#pragma unroll
    for (int j = 0; j < 16; j++) {
        const int row = idx[j];
        const float Tv = aB[j] * K2R[j] * b;
        Sc[row * 64 + lane] = 1024.0f * sv[j] * Tv;
        Tp[(long)(row * 64 + lane) * 256] = f2bf(Tv);
    }
}

extern "C" void kernel_launch(void* const* d_in, const int* in_sizes, int n_in,
                              void* d_out, int out_size, void* d_ws, size_t ws_size,
                              hipStream_t stream)
{
    (void)in_sizes; (void)n_in; (void)out_size; (void)ws_size;
    const float* xq = (const float*)d_in[0];
    const float* xk = (const float*)d_in[1];
    const float* xv = (const float*)d_in[2];
    const float* Wq = (const float*)d_in[3];
    const float* Wk = (const float*)d_in[4];
    const float* Wv = (const float*)d_in[5];
    const float* Wp = (const float*)d_in[6];
    const float* bp = (const float*)d_in[7];

    float* out_x     = (float*)d_out;           // (Nq,M,B,C) = 8192 x 512
    float* out_score = out_x + 8192L * 512;     // (B,K,M,Nq) = 2048 x 1024

    // workspace (47 MB of the proven 48 MB); regions reused across phases
    char* W = (char*)d_ws;
    const long MB = 1 << 20;
    unsigned short* qh   = (unsigned short*)(W + 0);        // 8MB [b][mn][c]
    unsigned short* ql   = (unsigned short*)(W + 8 * MB);   // 8MB
    unsigned short* xq_h = (unsigned short*)(W + 16 * MB);  // 8MB, dead after qkv
    float*          simb = (float*)(W + 16 * MB);           // 8MB (reuse)
    unsigned short* xq_l = (unsigned short*)(W + 24 * MB);  // 8MB, dead after qkv
    unsigned short* xpre = (unsigned short*)(W + 24 * MB);  // 8MB (reuse)
    unsigned short* xk_h = (unsigned short*)(W + 32 * MB);  // 2MB, dead after qkv
    unsigned short* xk_l = (unsigned short*)(W + 34 * MB);  // 2MB
    unsigned short* Tt   = (unsigned short*)(W + 32 * MB);  // 4MB (reuse)
    unsigned short* xv_b = (unsigned short*)(W + 36 * MB);  // 2MB
    unsigned short* kh   = (unsigned short*)(W + 38 * MB);  // 2MB [b][k'][c]
    unsigned short* kl   = (unsigned short*)(W + 40 * MB);  // 2MB
    unsigned short* vt   = (unsigned short*)(W + 42 * MB);  // 2MB [b][c][k']
    unsigned short* wqh  = (unsigned short*)(W + 44 * MB);
    unsigned short* wql  = (unsigned short*)(W + 44 * MB + 1 * 524288);
    unsigned short* wkh  = (unsigned short*)(W + 44 * MB + 2 * 524288);
    unsigned short* wkl  = (unsigned short*)(W + 44 * MB + 3 * 524288);
    unsigned short* wvb  = (unsigned short*)(W + 44 * MB + 4 * 524288);
    unsigned short* wpb  = (unsigned short*)(W + 44 * MB + 5 * 524288);

    const dim3 blk(256);

    // 1: precast/split all fp32 operands (memory-bound, one dispatch)
    prep<<<7168, blk, 0, stream>>>(xq, xk, xv, Wq, Wk, Wv, Wp,
                                   xq_h, xq_l, xk_h, xk_l, xv_b,
                                   wqh, wql, wkh, wkl, wvb, wpb);

    // 2: fused q/k/v projections (64x128 tiles, 3/CU, gll_lds dbuf)
    gemm_qkv2<<<dim3(192, 4), blk, 0, stream>>>(
        xq_h, xq_l, xk_h, xk_l, xv_b, wqh, wql, wkh, wkl, wvb,
        qh, ql, kh, kl, vt);

    // 3: sim[b][k'][mn] = (k.q) * rs_k * rs_q  (gll_lds dbuf, fragment
    //    norms, XCD-chunked swizzle: one batch per XCD)
    gemm_sim64<<<dim3(4, 16, 8), blk, 0, stream>>>(
        (const unsigned short*)kh, (const unsigned short*)kl,
        (const unsigned short*)qh, (const unsigned short*)ql,
        simb);

    // 4: Sinkhorn -> score (out) + T bf16 [b][mn][k']
    sinkhorn5<<<512, blk, 0, stream>>>(simb, out_score, Tt);

    // 5: xpre[b][mn][c] = sum_k' T[b][mn][k'] * v[b][k'][c]
    gemm_bf16_v2<false, false, true><<<dim3(16, 4, 8), blk, 0, stream>>>(
        Tt, vt, nullptr, xpre,
        256, 256, 256, 512, 262144, 131072, 524288);

    // 6: x = xpre @ Wp^T + bp, rows (b,mn)->(n,m,b), fp32 out
    gemm_bf16_v2<true, true, false><<<dim3(128, 4), blk, 0, stream>>>(
        xpre, wpb, bp, out_x,
        512, 512, 512, 512, 0, 0, 0);
}